// Round 7
// baseline (32.706 us; speedup 1.0000x reference)
//
#include <hip/hip_runtime.h>
#include <math.h>

#define Bn   512
#define Tn   50
#define NAn  5
#define NCn  7
#define GHn  16
#define GWn  32
#define PC   (GHn*GWn)            // 512 cells per anchor plane
#define CELLS (NAn*PC)            // 2560 cells per batch
#define EXCL  0x8000
#define TICK_OFF 12288            // byte offset of tickets in ws (after 6*512 f32)

__device__ __constant__ float c_aw[NAn] = {1.0f, 2.0f, 3.5f, 5.0f, 8.0f};
__device__ __constant__ float c_ah[NAn] = {1.5f, 3.0f, 4.5f, 6.0f, 10.0f};

__device__ inline float sigm(float v) { return 1.0f / (1.0f + __expf(-v)); }
// -log(clip(1-sigmoid(v),1e-12)) == softplus(v) exactly for v < 27.6 (|v|<6 here)
__device__ inline float softplus(float v) {
  return fmaxf(v, 0.0f) + __logf(1.0f + __expf(-fabsf(v)));
}

__device__ inline float wred(float v) {
#pragma unroll
  for (int off = 32; off > 0; off >>= 1) v += __shfl_down(v, off, 64);
  return v;
}

// Single fused kernel: one block per batch; partials via agent-scope stores;
// two-level ticket (8 sub-tickets, 64B apart, then 1 final); last block
// re-reads partials with agent-scope loads and finalizes.
__global__ __launch_bounds__(256) void k_all(const float* __restrict__ x,
                                             const float* __restrict__ tg,
                                             float* __restrict__ part,
                                             int* __restrict__ tick,
                                             float* __restrict__ out)
{
  const int b   = blockIdx.x;
  const int tid = threadIdx.x;

  // ---- issue conf loads FIRST (independent of LDS): 2 cells per anchor ----
  const float* xb = x + (size_t)b * (NAn * 14) * PC;
  float2 pc[NAn];
#pragma unroll
  for (int a = 0; a < NAn; ++a)
    pc[a] = *reinterpret_cast<const float2*>(xb + (a * 14 + 6) * PC + tid * 2);

  // ---- cooperative tg load into LDS (coalesced), also independent ----
  __shared__ float s_tg[Tn * 5];                  // 250 floats
  if (tid < Tn * 5) s_tg[tid] = tg[(size_t)b * (Tn * 5) + tid];

  __shared__ int   s_owner[CELLS];   // last-wins target tid per cell, -1 none
  __shared__ int   s_flags[CELLS];   // bits0..6 label set; bit15 mask|ignore
  __shared__ float s_tx[Tn], s_ty[Tn], s_tw[Tn], s_th[Tn];
  __shared__ float red6[4][6];
  __shared__ int   s_last;

#pragma unroll
  for (int i = 0; i < CELLS / 256; ++i) { s_owner[tid + i * 256] = -1; s_flags[tid + i * 256] = 0; }
  __syncthreads();

  // ---- target phase: O(T) owner-map build from LDS-resident targets ----
  if (tid < Tn) {
    float c0 = s_tg[tid * 5 + 0], c1 = s_tg[tid * 5 + 1], c2 = s_tg[tid * 5 + 2];
    float c3 = s_tg[tid * 5 + 3], c4 = s_tg[tid * 5 + 4];
    bool valid = (c0 + c1 + c2 + c3 + c4) > 0.0f;
    float gx = c1 * (float)GWn, gy = c2 * (float)GHn;
    float gw = c3 * (float)GWn, gh = c4 * (float)GHn;
    float iou[NAn];
    int best = 0; float bestv = -1.0f;
#pragma unroll
    for (int q = 0; q < NAn; ++q) {
      float inter = fminf(gw, c_aw[q]) * fminf(gh, c_ah[q]);
      float u = inter / (gw * gh + c_aw[q] * c_ah[q] - inter + 1e-16f);
      iou[q] = u;
      if (u > bestv) { bestv = u; best = q; }     // first-max like argmax
    }
    int gi = (int)floorf(gx), gj = (int)floorf(gy);
    bool inb = (gi >= 0) && (gi < GWn) && (gj >= 0) && (gj < GHn); // mode='drop'
    s_tx[tid] = gx - floorf(gx);
    s_ty[tid] = gy - floorf(gy);
    s_tw[tid] = logf(gw / c_aw[best] + 1e-16f);
    s_th[tid] = logf(gh / c_ah[best] + 1e-16f);
    if (valid && inb) {
      int pcell = gj * GWn + gi;
      int cell  = best * PC + pcell;
      atomicMax(&s_owner[cell], tid);             // last-wins = max tid
      int lbl = (int)c0;
      int lb  = (lbl >= 0 && lbl < NCn) ? (1 << lbl) : 0;  // mode='drop'
      atomicOr(&s_flags[cell], lb | EXCL);
#pragma unroll
      for (int q = 0; q < NAn; ++q) if (iou[q] > 0.6f)
        atomicOr(&s_flags[q * PC + pcell], EXCL);
    }
  }
  __syncthreads();

  // ---- sweep: conf already in registers; 2 cells per anchor per thread ----
  float v_mse = 0.f, v_pc = 0.f, v_cls = 0.f, v_neg = 0.f, v_np = 0.f, v_nc = 0.f;
#pragma unroll
  for (int a = 0; a < NAn; ++a) {
    const float p6v[2] = {pc[a].x, pc[a].y};
    const float* pl = xb + a * 14 * PC;
#pragma unroll
    for (int u = 0; u < 2; ++u) {
      int pcell = tid * 2 + u;
      int cell  = a * PC + pcell;
      int flags = s_flags[cell];
      float p6  = p6v[u];
      if (!(flags & EXCL)) {                      // negative cell
        v_neg += softplus(p6);                    // == -log(1-sigm(p6))
        v_nc  += 1.0f;
      }
      int owner = s_owner[cell];
      if (owner >= 0) {                           // positive (masked) cell
        float p0 = pl[0 * PC + pcell];
        float p1 = pl[1 * PC + pcell];
        float p2 = pl[2 * PC + pcell];
        float p3 = pl[3 * PC + pcell];
        float dx = sigm(p0) - s_tx[owner];
        float dy = sigm(p1) - s_ty[owner];
        float dw = p2 - s_tw[owner];
        float dh = p3 - s_th[owner];
        v_mse += dx * dx + dy * dy + dw * dw + dh * dh;
        v_pc  += softplus(-p6);                   // == -log(sigm(p6))
        v_np  += 1.0f;
        int bits = flags & 0x7F;
        if (bits) {
          float s[NCn]; float m = -1e30f;
#pragma unroll
          for (int k = 0; k < NCn; ++k) {
            s[k] = sigm(pl[(size_t)(7 + k) * PC + pcell]);
            m = fmaxf(m, s[k]);
          }
          float ssum = 0.f;
#pragma unroll
          for (int k = 0; k < NCn; ++k) ssum += __expf(s[k] - m);
          float lse = m + __logf(ssum);
#pragma unroll
          for (int k = 0; k < NCn; ++k)
            if ((bits >> k) & 1) v_cls += lse - s[k];
        }
      }
    }
  }

  // ---- block reduction, agent-scope store to private slot ----
  float vals[6] = {v_mse, v_pc, v_cls, v_neg, v_np, v_nc};
  int wid = tid >> 6, lane = tid & 63;
#pragma unroll
  for (int k = 0; k < 6; ++k) {
    float r = wred(vals[k]);
    if (lane == 0) red6[wid][k] = r;
  }
  __syncthreads();
  if (tid < 6) {
    float s = red6[0][tid] + red6[1][tid] + red6[2][tid] + red6[3][tid];
    __hip_atomic_store(&part[(size_t)tid * Bn + b], s,
                       __ATOMIC_RELAXED, __HIP_MEMORY_SCOPE_AGENT);
  }
  __syncthreads();

  // ---- completion tickets: 8 sub-tickets (64B apart) then final ----
  if (tid == 0) {
    __threadfence();
    int last = 0;
    int o = atomicAdd(&tick[(b & 7) * 16], 1);
    if (o == (Bn / 8) - 1) {
      int o2 = atomicAdd(&tick[128], 1);
      last = (o2 == 7) ? 1 : 0;
    }
    s_last = last;
  }
  __syncthreads();

  // ---- last block finalizes: re-read all partials with agent loads ----
  if (s_last) {
    float v[6];
#pragma unroll
    for (int k = 0; k < 6; ++k)
      v[k] = __hip_atomic_load(&part[(size_t)k * Bn + tid],
                               __ATOMIC_RELAXED, __HIP_MEMORY_SCOPE_AGENT)
           + __hip_atomic_load(&part[(size_t)k * Bn + tid + 256],
                               __ATOMIC_RELAXED, __HIP_MEMORY_SCOPE_AGENT);
#pragma unroll
    for (int k = 0; k < 6; ++k) {
      float r = wred(v[k]);
      if (lane == 0) red6[wid][k] = r;
    }
    __syncthreads();
    if (tid == 0) {
      float a0 = red6[0][0] + red6[1][0] + red6[2][0] + red6[3][0];
      float a1 = red6[0][1] + red6[1][1] + red6[2][1] + red6[3][1];
      float a2 = red6[0][2] + red6[1][2] + red6[2][2] + red6[3][2];
      float a3 = red6[0][3] + red6[1][3] + red6[2][3] + red6[3][3];
      float a4 = red6[0][4] + red6[1][4] + red6[2][4] + red6[3][4];
      float a5 = red6[0][5] + red6[1][5] + red6[2][5] + red6[3][5];
      float npos = fmaxf(a4, 1.0f);
      float negc = fmaxf(a5, 1.0f);
      out[0] = a0 / npos + a3 / negc + a1 / npos + a2 / ((float)Bn * npos);
    }
  }
}

extern "C" void kernel_launch(void* const* d_in, const int* in_sizes, int n_in,
                              void* d_out, int out_size, void* d_ws, size_t ws_size,
                              hipStream_t stream)
{
  const float* x  = (const float*)d_in[0];
  const float* tg = (const float*)d_in[1];
  float* part = (float*)d_ws;                       // 6*512 f32 = 12 KB
  int*   tick = (int*)((char*)d_ws + TICK_OFF);     // 8 sub (64B apart) + final

  hipMemsetAsync((char*)d_ws + TICK_OFF, 0, 1024, stream);
  k_all<<<Bn, 256, 0, stream>>>(x, tg, part, tick, (float*)d_out);
}